// Round 1
// baseline (59.104 us; speedup 1.0000x reference)
//
#include <hip/hip_runtime.h>

// BezierGlyph R6: anchored-logsumexp, 4-wave 8x8 tiles (sample-split).
// 4096 blocks x 256 threads; block = one 8x8 pixel tile, 4 waves.
// Each wave owns every 4th 4-sample chunk of the culled list; per-pixel
// partial sums are combined through LDS. Rationale: R5 had only 4
// waves/SIMD and hot tiles ran as single waves with exposed trans/LDS
// latency; this spreads each hot tile across all 4 SIMDs of its CU and
// lifts occupancy 4x.
//
// Anchor identity: for wave-uniform A <= min_k d_k (all pixels/samples),
//   md = A - log2( sum_k exp2(C*(A - d_k)) ) / C       (C = 256*log2 e)
// is EXACT logsumexp — no per-pixel min pass required. We take
//   A = sqrt( min_samples bb2 ),  bb2 = squared dist(sample, tile bbox),
// so every term <= 1 (no overflow).
// Cull: max_px(min d) <= A + 2*HD, so one list with threshold
//   T = min(A + 2*HD, FARCUT) + RADIUS
// keeps all terms that matter; dropped terms each < exp(-256*0.06) ~ 2e-7,
// and pixels with d > FARCUT saturate to out = 1 within 7.5e-6.
// Far tile: A > FARCUT -> out = 1 immediately.

#define SIZE 512
#define RADIUS 0.06f
#define FARCUT 0.1217f          // 0.04 + ln(256)/256 + RADIUS
#define HB 0.00684932f          // 3.5/511         (pixel-center bbox half-extent)
#define HD 0.00968631f          // HB*sqrt(2)      (bbox half-diagonal)

__device__ __forceinline__ float clamp01(float x) {
    return fminf(fmaxf(x, 0.0f), 1.0f);
}
__device__ __forceinline__ float wave_min(float v) {
    #pragma unroll
    for (int m = 1; m < 64; m <<= 1) v = fminf(v, __shfl_xor(v, m));
    return v;
}

__global__ __launch_bounds__(256) void bezier_glyph_kernel(
        const float* __restrict__ cp,   // (8,4,2) control points
        float* __restrict__ out)        // (512*512)
{
    __shared__ float2 list[264];
    __shared__ float  wred[4];
    __shared__ int    cnt[4];
    __shared__ float  part[4][64];

    const int tid  = threadIdx.x;       // 0..255
    const int w    = tid >> 6;          // wave 0..3
    const int lane = tid & 63;
    const int b    = blockIdx.x;
    const int row_base = (b >> 6) << 3;
    const int col_base = (b & 63) << 3;
    const float inv = 1.0f / 511.0f;
    const float cx  = ((float)col_base + 3.5f) * inv;
    const float cy  = ((float)row_base + 3.5f) * inv;

    // ---- Stage 0: thread t evaluates sample t (stroke t>>5, Horner) ----
    float sx, sy, bb2;
    {
        const int s = tid >> 5;
        const float* p = cp + s * 8;
        const float x0 = clamp01(p[0]), y0 = clamp01(p[1]);
        const float x1 = clamp01(p[2]), y1 = clamp01(p[3]);
        const float x2 = clamp01(p[4]), y2 = clamp01(p[5]);
        const float x3 = clamp01(p[6]), y3 = clamp01(p[7]);
        const float c1x = 3.0f * (x1 - x0);
        const float c2x = 3.0f * (x0 - 2.0f * x1 + x2);
        const float c3x = x3 - x0 + 3.0f * (x1 - x2);
        const float c1y = 3.0f * (y1 - y0);
        const float c2y = 3.0f * (y0 - 2.0f * y1 + y2);
        const float c3y = y3 - y0 + 3.0f * (y1 - y2);
        const float u   = (float)(tid & 31) * (1.0f / 31.0f);
        sx = fmaf(fmaf(fmaf(c3x, u, c2x), u, c1x), u, x0);
        sy = fmaf(fmaf(fmaf(c3y, u, c2y), u, c1y), u, y0);
        const float bx = fmaxf(fabsf(sx - cx) - HB, 0.0f);
        const float by = fmaxf(fabsf(sy - cy) - HB, 0.0f);
        bb2 = fmaf(bx, bx, by * by);
    }

    // ---- anchor: A = sqrt(min over all 256 samples of bb2) ----
    const float wm = wave_min(bb2);
    if (lane == 0) wred[w] = wm;
    __syncthreads();
    const float A = __builtin_amdgcn_sqrtf(
        fminf(fminf(wred[0], wred[1]), fminf(wred[2], wred[3])));

    const int row = row_base + (lane >> 3);
    const int col = col_base + (lane & 7);

    if (A > FARCUT) {                   // whole tile far: out == 1 (+-7.5e-6)
        if (w == 0) out[row * SIZE + col] = 1.0f;
        return;                         // block-uniform: no barrier skipped
    }

    // ---- build the single culled list (per-wave ballot + cross-wave prefix) ----
    const float T   = fminf(A + 2.0f * HD, FARCUT) + RADIUS + 1e-4f;
    const float Ts  = T * T;
    const bool  keep = (bb2 <= Ts);
    const unsigned long long mk = __ballot(keep);
    const unsigned long long lt = (1ull << lane) - 1ull;
    if (lane == 0) cnt[w] = (int)__popcll(mk);
    __syncthreads();
    const int c0 = cnt[0], c1 = cnt[1], c2 = cnt[2], c3 = cnt[3];
    const int n  = c0 + c1 + c2 + c3;
    int off = 0;
    if (w > 0) off += c0;
    if (w > 1) off += c1;
    if (w > 2) off += c2;
    if (keep) list[off + (int)__popcll(mk & lt)] = make_float2(sx, sy);
    if (tid < 4) list[n + tid] = make_float2(1e3f, 1e3f);  // pad -> exp2 -> 0
    __syncthreads();

    // ---- fused pass: wave w sums its quarter of S = sum exp2(C*(A - d_k)) ----
    const float py = (float)row * inv;
    const float px = (float)col * inv;
    const float C  = 369.3299304675766f;   // 256 * log2(e)
    const float nC = -C;
    const float cA = C * A;
    float S0 = 0.0f, S1 = 0.0f, S2 = 0.0f, S3 = 0.0f;
    const int nr = (n + 3) & ~3;
    for (int k = (w << 2); k < nr; k += 16) {
        const float2 a = list[k],     b2 = list[k + 1];
        const float2 c = list[k + 2], e  = list[k + 3];
        float dx, dy;
        dx = px - a.x;  dy = py - a.y;  const float qa = fmaf(dx, dx, dy * dy);
        dx = px - b2.x; dy = py - b2.y; const float qb = fmaf(dx, dx, dy * dy);
        dx = px - c.x;  dy = py - c.y;  const float qc = fmaf(dx, dx, dy * dy);
        dx = px - e.x;  dy = py - e.y;  const float qe = fmaf(dx, dx, dy * dy);
        S0 += __builtin_amdgcn_exp2f(fmaf(nC, __builtin_amdgcn_sqrtf(qa), cA));
        S1 += __builtin_amdgcn_exp2f(fmaf(nC, __builtin_amdgcn_sqrtf(qb), cA));
        S2 += __builtin_amdgcn_exp2f(fmaf(nC, __builtin_amdgcn_sqrtf(qc), cA));
        S3 += __builtin_amdgcn_exp2f(fmaf(nC, __builtin_amdgcn_sqrtf(qe), cA));
    }
    part[w][lane] = (S0 + S1) + (S2 + S3);
    __syncthreads();

    if (w == 0) {
        const float S = (part[0][lane] + part[1][lane])
                      + (part[2][lane] + part[3][lane]);
        // md = A - log2(S)/C  (exact logsumexp given the anchor)
        // S==0 (all terms underflow) -> md = +inf -> out = 1: correct.
        const float md = A - __builtin_amdgcn_logf(S) * (1.0f / C);
        const float K  = 288.53900817779268f;  // 200 * log2(e)
        out[row * SIZE + col] = __builtin_amdgcn_rcpf(
            1.0f + __builtin_amdgcn_exp2f((0.04f - md) * K));
    }
}

extern "C" void kernel_launch(void* const* d_in, const int* in_sizes, int n_in,
                              void* d_out, int out_size, void* d_ws, size_t ws_size,
                              hipStream_t stream) {
    const float* cp = (const float*)d_in[0];   // control_points (8,4,2)
    float* out = (float*)d_out;                // pixel_grid recomputed in-kernel
    bezier_glyph_kernel<<<dim3(4096), dim3(256), 0, stream>>>(cp, out);
}